// Round 19
// baseline (142.696 us; speedup 1.0000x reference)
//
#include <hip/hip_runtime.h>
#include <hip/hip_fp16.h>

// Problem constants (static from reference setup_inputs)
constexpr int BB = 8, CC = 4, HH = 1024, WW = 1024, CROP = 5;
constexpr int HC = HH - 2 * CROP, WC = WW - 2 * CROP;   // 1014 x 1014
constexpr int HW = HH * WW;
constexpr float AA = -0.75f;                            // PyTorch bicubic A

constexpr int NSTRIP = 16;                 // vertical strips (64 rows each)
constexpr int GRID = 32 * NSTRIP * 2;      // x2 channel-pairs = 1024 = 4/CU
constexpr int RING = 16;                   // row slots (slot = row & 15)
constexpr int SWID = 272;                  // dwords per slot: A[0..135] B[136..271]
constexpr int CH_STRIDE = RING * SWID;     // 4352 dwords per channel
// LDS per block: 2 ch x 4352 x 4B = 34816 B -> 4 blocks/CU

typedef float f4 __attribute__((ext_vector_type(4)));
typedef f4 uf4 __attribute__((aligned(4)));

// reflection valid for |i| <= 2046
__device__ __forceinline__ int reflect_small(int i) {
    int r = i < 0 ? -i : i;
    return r > (HH - 1) ? 2 * (HH - 1) - r : r;
}

__device__ __forceinline__ void cubic_w(float t, float& w0, float& w1,
                                        float& w2, float& w3) {
    float t1 = t + 1.0f;
    w0 = ((AA * t1 - 5.0f * AA) * t1 + 8.0f * AA) * t1 - 4.0f * AA;
    w1 = ((AA + 2.0f) * t - (AA + 3.0f)) * t * t + 1.0f;
    float s = 1.0f - t;
    w2 = ((AA + 2.0f) * s - (AA + 3.0f)) * s * s + 1.0f;
    float s2 = 2.0f - t;
    w3 = ((AA * s2 - 5.0f * AA) * s2 + 8.0f * AA) * s2 - 4.0f * AA;
}

// rare fallback (~1e-4 of pixels): reflected global taps, f32-exact
__device__ __noinline__ float px_slow2(const float* __restrict__ tgt_p,
                                       const float* __restrict__ in_p, int pix,
                                       int bx, int by, float wx0, float wx1,
                                       float wx2, float wx3, float wy0,
                                       float wy1, float wy2, float wy3) {
    const int r0 = reflect_small(by - 1) * WW;
    const int r1 = reflect_small(by) * WW;
    const int r2 = reflect_small(by + 1) * WW;
    const int r3 = reflect_small(by + 2) * WW;
    const int c0 = reflect_small(bx - 1);
    const int c1 = reflect_small(bx);
    const int c2 = reflect_small(bx + 1);
    const int c3 = reflect_small(bx + 2);
    float acc = 0.0f;
#pragma unroll
    for (int c = 0; c < 2; ++c) {
        const float* tb = tgt_p + c * HW;
        float q0 = wx0 * tb[r0 + c0] + wx1 * tb[r0 + c1] + wx2 * tb[r0 + c2] +
                   wx3 * tb[r0 + c3];
        float q1 = wx0 * tb[r1 + c0] + wx1 * tb[r1 + c1] + wx2 * tb[r1 + c2] +
                   wx3 * tb[r1 + c3];
        float q2 = wx0 * tb[r2 + c0] + wx1 * tb[r2 + c1] + wx2 * tb[r2 + c2] +
                   wx3 * tb[r2 + c3];
        float q3 = wx0 * tb[r3 + c0] + wx1 * tb[r3 + c1] + wx2 * tb[r3 + c2] +
                   wx3 * tb[r3 + c3];
        float v = wy0 * q0 + wy1 * q1 + wy2 * q2 + wy3 * q3;
        acc += fabsf(in_p[c * HW + pix] - v);
    }
    return acc;
}

// pack two f32 -> one dword of 2 f16 (round-nearest)
__device__ __forceinline__ unsigned pk(float a, float b) {
    __half2 h = __floats2half2_rn(a, b);
    return __builtin_bit_cast(unsigned, h);
}

__global__ __launch_bounds__(256, 4) void warp_loss_k(
    const float* __restrict__ input, const float* __restrict__ target,
    const float* __restrict__ flow, float* __restrict__ wsbuf) {
    // per channel: slot s dwords [s*272 .. +135]=phase A, [+136..+271]=phase B
    __shared__ unsigned cacheU[2 * CH_STRIDE];   // 34816 B
    const int tid = (int)threadIdx.x;
    const int wv = tid >> 6, lane = tid & 63;

    // pair bit HIGH so pair partners (idx +/-512) land on the same XCD (mod 8)
    const int low = (int)blockIdx.x & 511;
    const int pair = (int)blockIdx.x >> 9;    // 0: ch {0,1}, 1: ch {2,3}
    const int colid = low >> 4;               // (b, chunk)
    const int strip = low & 15;
    const int b = colid >> 2;
    const int chunk = colid & 3;
    const int x0 = CROP + chunk * 256;
    // window start col: [wscol, wscol+271] in-image, ~±7σ margins
    const int wscol = chunk == 0 ? 0 : chunk == 1 ? 252 : chunk == 2 ? 508 : 752;
    const int y0 = CROP + strip * 64;
    const int y1 = min(y0 + 64, CROP + HC);   // exclusive

    const int x = x0 + tid;
    const bool valid_px = x <= 1018;
    const int xc = valid_px ? x : 1018;

    const float* tgt_p = target + (size_t)b * CC * HW + (size_t)(pair * 2) * HW;
    const float* in_p = input + (size_t)b * CC * HW + (size_t)(pair * 2) * HW;
    const float* flow_b = flow + (size_t)b * 2 * HW;

    // staging: wave wv = channel (wv>>1), part q = wv&1.
    //   k1 = lane + q*64 in [0,127]; part0 lanes 0..7 also cover k2 in [128,135].
    //   k <= 134: f4 load at 2k gives t[2k..2k+3] -> A[k]=pk(t2k,t2k+1),
    //             B[k]=pk(t2k+1,t2k+2).
    //   k == 135: float2 load (floats 270,271 only; f4 would run OOB at
    //             wscol=752) -> A[135]=pk(t270,t271), B[135]=dummy (never read:
    //             max odd cx=267 reads B[133],B[134]).
    const int chv = wv >> 1, q = wv & 1;
    const float* plane = tgt_p + (size_t)chv * HW;
    const int chbase = chv * CH_STRIDE;
    const int k1 = lane + q * 64;
    const bool has_k2 = (q == 0) && (lane < 8);
    const int k2 = lane + 128;                // 128..135

    // prologue: rows y0-5 .. y0+5 (in [0,1023], no reflection)
#pragma unroll 1
    for (int kk = 0; kk < 11; ++kk) {
        const int r = y0 - 5 + kk;
        const int sb = chbase + (r & (RING - 1)) * SWID;
        const float* src = plane + (size_t)r * WW + wscol;
        {
            f4 g = *(const uf4*)(src + 2 * k1);
            cacheU[sb + k1] = pk(g.x, g.y);
            cacheU[sb + 136 + k1] = pk(g.y, g.z);
        }
        if (has_k2) {
            if (k2 < 135) {
                f4 g = *(const uf4*)(src + 2 * k2);
                cacheU[sb + k2] = pk(g.x, g.y);
                cacheU[sb + 136 + k2] = pk(g.y, g.z);
            } else {
                float2 g = *(const float2*)(src + 270);
                cacheU[sb + 135] = pk(g.x, g.y);
                cacheU[sb + 136 + 135] = pk(g.y, 0.0f);
            }
        }
    }

    // scalar-stream prefetch for first row
    float dxn = flow_b[y0 * WW + xc];
    float dyn = flow_b[HW + y0 * WW + xc];
    float i0n = in_p[y0 * WW + xc];
    float i1n = in_p[HW + y0 * WW + xc];

    __syncthreads();

    float lsum = 0.0f;

    for (int y = y0; y < y1; ++y) {
        const float dx = dxn, dy = dyn;
        const float i0v = i0n, i1v = i1n;

        // T14: issue next-row staging loads + next scalar prefetch FIRST
        const int r = y + 6;
        const bool do_stage = r < HH;   // wave-uniform
        f4 g1 = {0, 0, 0, 0};
        float2 g2l = {0, 0};
        f4 g2 = {0, 0, 0, 0};
        if (do_stage) {
            const float* src = plane + (size_t)r * WW + wscol;
            g1 = *(const uf4*)(src + 2 * k1);
            if (has_k2) {
                if (k2 < 135) g2 = *(const uf4*)(src + 2 * k2);
                else g2l = *(const float2*)(src + 270);
            }
        }
        {
            const int yn = (y + 1 < y1) ? y + 1 : y;
            const int pixn = yn * WW + xc;
            dxn = flow_b[pixn];
            dyn = flow_b[HW + pixn];
            i0n = in_p[pixn];
            i1n = in_p[HW + pixn];
        }

        const int pix = y * WW + xc;
        const float fx = (float)xc + dx;
        const float fy = (float)y + dy;
        const float bxf = floorf(fx), byf = floorf(fy);
        const int bx = (int)bxf, by = (int)byf;
        const float tx = fx - bxf, ty = fy - byf;

        float wx0, wx1, wx2, wx3, wy0, wy1, wy2, wy3;
        cubic_w(tx, wx0, wx1, wx2, wx3);
        cubic_w(ty, wy0, wy1, wy2, wy3);

        const int d = by - y;
        const int cx = bx - 1 - wscol;
        const bool fast =
            valid_px & (d >= -4) & (d <= 3) & (cx >= 0) & (cx <= 268);

        if (fast) {
            // phase-select: 2 dwords = 4 f16 taps per channel-row
            const int idx = (cx >> 1) + ((cx & 1) * 136);
            const int t0 = (by - 1) & (RING - 1);
            float v0 = 0.0f, v1 = 0.0f;
#pragma unroll
            for (int j = 0; j < 4; ++j) {
                const int s = (t0 + j) & (RING - 1);
                const int a0 = s * SWID + idx;
                const float wyj =
                    j == 0 ? wy0 : j == 1 ? wy1 : j == 2 ? wy2 : wy3;
                {
                    unsigned d0 = cacheU[a0];
                    unsigned d1 = cacheU[a0 + 1];
                    float2 f0 = __half22float2(__builtin_bit_cast(__half2, d0));
                    float2 f1 = __half22float2(__builtin_bit_cast(__half2, d1));
                    v0 += wyj * (f0.x * wx0 + f0.y * wx1 + f1.x * wx2 + f1.y * wx3);
                }
                {
                    unsigned d0 = cacheU[CH_STRIDE + a0];
                    unsigned d1 = cacheU[CH_STRIDE + a0 + 1];
                    float2 f0 = __half22float2(__builtin_bit_cast(__half2, d0));
                    float2 f1 = __half22float2(__builtin_bit_cast(__half2, d1));
                    v1 += wyj * (f0.x * wx0 + f0.y * wx1 + f1.x * wx2 + f1.y * wx3);
                }
            }
            lsum += fabsf(i0v - v0) + fabsf(i1v - v1);
        } else if (valid_px) {
            lsum += px_slow2(tgt_p, in_p, pix, bx, by, wx0, wx1, wx2, wx3,
                             wy0, wy1, wy2, wy3);
        }

        // write staged row y+6 (slot holds row y-10, outside window y-5..y+5)
        if (do_stage) {
            const int sb = chbase + (r & (RING - 1)) * SWID;
            cacheU[sb + k1] = pk(g1.x, g1.y);
            cacheU[sb + 136 + k1] = pk(g1.y, g1.z);
            if (has_k2) {
                if (k2 < 135) {
                    cacheU[sb + k2] = pk(g2.x, g2.y);
                    cacheU[sb + 136 + k2] = pk(g2.y, g2.z);
                } else {
                    cacheU[sb + 135] = pk(g2l.x, g2l.y);
                    cacheU[sb + 136 + 135] = pk(g2l.y, 0.0f);
                }
            }
        }

        // writes visible + all reads of old window done before slot reuse
        __syncthreads();
    }

    // wave-64 shuffle reduction + per-block partial (no global atomic)
#pragma unroll
    for (int off2 = 32; off2 > 0; off2 >>= 1) lsum += __shfl_down(lsum, off2);

    __shared__ float sm[4];
    if (lane == 0) sm[wv] = lsum;
    __syncthreads();
    if (tid == 0) wsbuf[blockIdx.x] = sm[0] + sm[1] + sm[2] + sm[3];
}

__global__ __launch_bounds__(1024) void reduce_k(const float* __restrict__ ws,
                                                 float* __restrict__ out) {
    float s = 0.0f;
    for (int i = threadIdx.x; i < GRID; i += 1024) s += ws[i];
#pragma unroll
    for (int off = 32; off > 0; off >>= 1) s += __shfl_down(s, off);
    __shared__ float sm[16];
    const int lane = threadIdx.x & 63;
    const int wv = threadIdx.x >> 6;
    if (lane == 0) sm[wv] = s;
    __syncthreads();
    if (threadIdx.x == 0) {
        float t = 0.0f;
#pragma unroll
        for (int i = 0; i < 16; ++i) t += sm[i];
        constexpr float inv_count = 1.0f / ((float)BB * CC * HC * WC);
        out[0] = t * inv_count;
    }
}

extern "C" void kernel_launch(void* const* d_in, const int* in_sizes, int n_in,
                              void* d_out, int out_size, void* d_ws,
                              size_t ws_size, hipStream_t stream) {
    const float* input = (const float*)d_in[0];
    const float* target = (const float*)d_in[1];
    const float* flow = (const float*)d_in[2];
    float* ws = (float*)d_ws;
    float* out = (float*)d_out;

    warp_loss_k<<<GRID, 256, 0, stream>>>(input, target, flow, ws);
    reduce_k<<<1, 1024, 0, stream>>>(ws, out);
}

// Round 20
// 120.488 us; speedup vs baseline: 1.1843x; 1.1843x over previous
//
#include <hip/hip_runtime.h>

// Problem constants (static from reference setup_inputs)
constexpr int BB = 8, CC = 4, HH = 1024, WW = 1024, CROP = 5;
constexpr int HC = HH - 2 * CROP, WC = WW - 2 * CROP;   // 1014 x 1014
constexpr int HW = HH * WW;
constexpr float AA = -0.75f;                            // PyTorch bicubic A

constexpr int NSTRIP = 16;                 // vertical strips (64 rows each)
constexpr int GRID = 32 * NSTRIP * 2;      // x2 channel-pairs = 1024 = 4/CU
constexpr int RING = 16;                   // row slots (slot = row & 15)
constexpr int SWID = 284;                  // LDS row stride (floats). 284%32=28:
                                           // bank=(28*s+cx)%32 -> 16-apart lane
                                           // pairs need ds==4 (P~0.3%) vs
                                           // SWID=272's ds-odd (P~50%) 4-ways.
                                           // 284*4 % 16 == 0: gll dest aligned.
constexpr int SDATA = 272;                 // staged data cols per slot
constexpr int CH_STRIDE = RING * SWID;     // 4544 floats per channel
// LDS per block: 2 ch x 4544 x 4B = 36352 B -> 4 blocks/CU

typedef __attribute__((address_space(1))) const void gv_t;
typedef __attribute__((address_space(3))) void lv_t;

// reflection valid for |i| <= 2046
__device__ __forceinline__ int reflect_small(int i) {
    int r = i < 0 ? -i : i;
    return r > (HH - 1) ? 2 * (HH - 1) - r : r;
}

__device__ __forceinline__ void cubic_w(float t, float& w0, float& w1,
                                        float& w2, float& w3) {
    float t1 = t + 1.0f;
    w0 = ((AA * t1 - 5.0f * AA) * t1 + 8.0f * AA) * t1 - 4.0f * AA;
    w1 = ((AA + 2.0f) * t - (AA + 3.0f)) * t * t + 1.0f;
    float s = 1.0f - t;
    w2 = ((AA + 2.0f) * s - (AA + 3.0f)) * s * s + 1.0f;
    float s2 = 2.0f - t;
    w3 = ((AA * s2 - 5.0f * AA) * s2 + 8.0f * AA) * s2 - 4.0f * AA;
}

// rare fallback (~1e-4 of pixels): reflected global taps for TWO channels
__device__ __noinline__ float px_slow2(const float* __restrict__ tgt_p,
                                       const float* __restrict__ in_p, int pix,
                                       int bx, int by, float wx0, float wx1,
                                       float wx2, float wx3, float wy0,
                                       float wy1, float wy2, float wy3) {
    const int r0 = reflect_small(by - 1) * WW;
    const int r1 = reflect_small(by) * WW;
    const int r2 = reflect_small(by + 1) * WW;
    const int r3 = reflect_small(by + 2) * WW;
    const int c0 = reflect_small(bx - 1);
    const int c1 = reflect_small(bx);
    const int c2 = reflect_small(bx + 1);
    const int c3 = reflect_small(bx + 2);
    float acc = 0.0f;
#pragma unroll
    for (int c = 0; c < 2; ++c) {
        const float* tb = tgt_p + c * HW;
        float q0 = wx0 * tb[r0 + c0] + wx1 * tb[r0 + c1] + wx2 * tb[r0 + c2] +
                   wx3 * tb[r0 + c3];
        float q1 = wx0 * tb[r1 + c0] + wx1 * tb[r1 + c1] + wx2 * tb[r1 + c2] +
                   wx3 * tb[r1 + c3];
        float q2 = wx0 * tb[r2 + c0] + wx1 * tb[r2 + c1] + wx2 * tb[r2 + c2] +
                   wx3 * tb[r2 + c3];
        float q3 = wx0 * tb[r3 + c0] + wx1 * tb[r3 + c1] + wx2 * tb[r3 + c2] +
                   wx3 * tb[r3 + c3];
        float v = wy0 * q0 + wy1 * q1 + wy2 * q2 + wy3 * q3;
        acc += fabsf(in_p[c * HW + pix] - v);
    }
    return acc;
}

__global__ __launch_bounds__(256, 4) void warp_loss_k(
    const float* __restrict__ input, const float* __restrict__ target,
    const float* __restrict__ flow, float* __restrict__ wsbuf) {
    __shared__ float cache[2 * CH_STRIDE];    // 36.4 KB
    const int tid = (int)threadIdx.x;
    const int wv = tid >> 6, lane = tid & 63;

    // pair bit HIGH so pair partners (idx +/-512) land on the same XCD (mod 8)
    const int low = (int)blockIdx.x & 511;
    const int pair = (int)blockIdx.x >> 9;    // 0: ch {0,1}, 1: ch {2,3}
    const int colid = low >> 4;               // (b, chunk)
    const int strip = low & 15;
    const int b = colid >> 2;
    const int chunk = colid & 3;
    const int x0 = CROP + chunk * 256;
    // window start col: 4-aligned, [wscol, wscol+271] in-image, ~±7σ margins
    const int wscol = chunk == 0 ? 0 : chunk == 1 ? 252 : chunk == 2 ? 508 : 752;
    const int y0 = CROP + strip * 64;
    const int y1 = min(y0 + 64, CROP + HC);   // exclusive

    const int x = x0 + tid;
    const bool valid_px = x <= 1018;
    const int xc = valid_px ? x : 1018;

    // base pointers for this block's channel pair
    const float* tgt_p = target + (size_t)b * CC * HW + (size_t)(pair * 2) * HW;
    const float* in_p = input + (size_t)b * CC * HW + (size_t)(pair * 2) * HW;
    const float* flow_b = flow + (size_t)b * 2 * HW;

    // wave wv stages channel (wv>>1), part (wv&1): part0 = floats [0,255]
    // via 16B/lane; part1 = floats [208,271] via 4B/lane (overlap identical)
    const int chv = wv >> 1, part = wv & 1;
    const float* plane = tgt_p + (size_t)chv * HW;
    const int chbase = chv * CH_STRIDE;

    // prologue: rows y0-5 .. y0+5 (in [0,1023] -> no reflection)
#pragma unroll 1
    for (int k = 0; k < 11; ++k) {
        const int r = y0 - 5 + k;
        const int slot = r & (RING - 1);
        const float* src = plane + (size_t)r * WW + wscol;
        if (part == 0) {
            __builtin_amdgcn_global_load_lds(
                (gv_t*)(src + lane * 4), (lv_t*)&cache[chbase + slot * SWID],
                16, 0, 0);
        } else {
            __builtin_amdgcn_global_load_lds(
                (gv_t*)(src + 208 + lane),
                (lv_t*)&cache[chbase + slot * SWID + 208], 4, 0, 0);
        }
    }

    // scalar-stream prefetch for first row (consumed after first barrier)
    float dxn = flow_b[y0 * WW + xc];
    float dyn = flow_b[HW + y0 * WW + xc];
    float i0n = in_p[y0 * WW + xc];
    float i1n = in_p[HW + y0 * WW + xc];

    __syncthreads();

    float lsum = 0.0f;

    for (int y = y0; y < y1; ++y) {
        // consume prefetched scalar streams for this row
        const float dx = dxn, dy = dyn;
        const float i0v = i0n, i1v = i1n;

        // issue next row's scalar prefetch NOW (consumed after next barrier,
        // so the compiler cannot create a stall on it this iteration)
        {
            const int yn = (y + 1 < y1) ? y + 1 : y;
            const int pixn = yn * WW + xc;
            dxn = flow_b[pixn];
            dyn = flow_b[HW + pixn];
            i0n = in_p[pixn];
            i1n = in_p[HW + pixn];
        }

        // stage row y+6 (slot (y+6)&15 holds row y-10, outside window y-5..y+5)
        {
            const int r = y + 6;
            if (r < HH) {   // wave-uniform; last strip tail
                const int slot = r & (RING - 1);
                const float* src = plane + (size_t)r * WW + wscol;
                if (part == 0) {
                    __builtin_amdgcn_global_load_lds(
                        (gv_t*)(src + lane * 4),
                        (lv_t*)&cache[chbase + slot * SWID], 16, 0, 0);
                } else {
                    __builtin_amdgcn_global_load_lds(
                        (gv_t*)(src + 208 + lane),
                        (lv_t*)&cache[chbase + slot * SWID + 208], 4, 0, 0);
                }
            }
        }

        const int pix = y * WW + xc;
        const float fx = (float)xc + dx;
        const float fy = (float)y + dy;
        const float bxf = floorf(fx), byf = floorf(fy);
        const int bx = (int)bxf, by = (int)byf;
        const float tx = fx - bxf, ty = fy - byf;

        float wx0, wx1, wx2, wx3, wy0, wy1, wy2, wy3;
        cubic_w(tx, wx0, wx1, wx2, wx3);
        cubic_w(ty, wy0, wy1, wy2, wy3);

        const int d = by - y;
        const int cx = bx - 1 - wscol;
        const bool fast =
            valid_px & (d >= -4) & (d <= 3) & (cx >= 0) & (cx <= 268);

        if (fast) {
            const int t = (by - 1) & (RING - 1);
            float v0 = 0.0f, v1 = 0.0f;
#pragma unroll
            for (int j = 0; j < 4; ++j) {
                const int s = (t + j) & (RING - 1);
                const int base = s * SWID + cx;
                const float wyj =
                    j == 0 ? wy0 : j == 1 ? wy1 : j == 2 ? wy2 : wy3;
                const float* p0 = &cache[base];
                const float* p1 = &cache[CH_STRIDE + base];
                v0 += wyj * (p0[0] * wx0 + p0[1] * wx1 + p0[2] * wx2 + p0[3] * wx3);
                v1 += wyj * (p1[0] * wx0 + p1[1] * wx1 + p1[2] * wx2 + p1[3] * wx3);
            }
            lsum += fabsf(i0v - v0) + fabsf(i1v - v1);
        } else if (valid_px) {
            lsum += px_slow2(tgt_p, in_p, pix, bx, by, wx0, wx1, wx2, wx3,
                             wy0, wy1, wy2, wy3);
        }

        // stage(y+6) landed + all reads of this window done before slot reuse
        __syncthreads();
    }

    // wave-64 shuffle reduction + per-block partial (no global atomic)
#pragma unroll
    for (int off2 = 32; off2 > 0; off2 >>= 1) lsum += __shfl_down(lsum, off2);

    __shared__ float sm[4];
    if (lane == 0) sm[wv] = lsum;
    __syncthreads();
    if (tid == 0) wsbuf[blockIdx.x] = sm[0] + sm[1] + sm[2] + sm[3];
}

__global__ __launch_bounds__(1024) void reduce_k(const float* __restrict__ ws,
                                                 float* __restrict__ out) {
    float s = 0.0f;
    for (int i = threadIdx.x; i < GRID; i += 1024) s += ws[i];
#pragma unroll
    for (int off = 32; off > 0; off >>= 1) s += __shfl_down(s, off);
    __shared__ float sm[16];
    const int lane = threadIdx.x & 63;
    const int wv = threadIdx.x >> 6;
    if (lane == 0) sm[wv] = s;
    __syncthreads();
    if (threadIdx.x == 0) {
        float t = 0.0f;
#pragma unroll
        for (int i = 0; i < 16; ++i) t += sm[i];
        constexpr float inv_count = 1.0f / ((float)BB * CC * HC * WC);
        out[0] = t * inv_count;
    }
}

extern "C" void kernel_launch(void* const* d_in, const int* in_sizes, int n_in,
                              void* d_out, int out_size, void* d_ws,
                              size_t ws_size, hipStream_t stream) {
    const float* input = (const float*)d_in[0];
    const float* target = (const float*)d_in[1];
    const float* flow = (const float*)d_in[2];
    float* ws = (float*)d_ws;
    float* out = (float*)d_out;

    warp_loss_k<<<GRID, 256, 0, stream>>>(input, target, flow, ws);
    reduce_k<<<1, 1024, 0, stream>>>(ws, out);
}

// Round 21
// 108.950 us; speedup vs baseline: 1.3097x; 1.1059x over previous
//
#include <hip/hip_runtime.h>

// Problem constants (static from reference setup_inputs)
constexpr int BB = 8, CC = 4, HH = 1024, WW = 1024, CROP = 5;
constexpr int HC = HH - 2 * CROP, WC = WW - 2 * CROP;   // 1014 x 1014
constexpr int HW = HH * WW;
constexpr float AA = -0.75f;                            // PyTorch bicubic A

constexpr int NSTRIP = 16;                 // vertical strips (64 rows each)
constexpr int GRID = 32 * NSTRIP * 2;      // x2 channel-pairs = 1024 = 4/CU
constexpr int RING = 16;                   // row slots (slot = row & 15)
constexpr int SWID = 272;                  // floats per slot (256 + halo)
constexpr int CH_STRIDE = RING * SWID;     // 4352 floats per channel
// LDS per block: 2 ch x 4352 x 4B = 34816 B -> 4 blocks/CU

typedef __attribute__((address_space(1))) const void gv_t;
typedef __attribute__((address_space(3))) void lv_t;

// reflection valid for |i| <= 2046
__device__ __forceinline__ int reflect_small(int i) {
    int r = i < 0 ? -i : i;
    return r > (HH - 1) ? 2 * (HH - 1) - r : r;
}

__device__ __forceinline__ void cubic_w(float t, float& w0, float& w1,
                                        float& w2, float& w3) {
    float t1 = t + 1.0f;
    w0 = ((AA * t1 - 5.0f * AA) * t1 + 8.0f * AA) * t1 - 4.0f * AA;
    w1 = ((AA + 2.0f) * t - (AA + 3.0f)) * t * t + 1.0f;
    float s = 1.0f - t;
    w2 = ((AA + 2.0f) * s - (AA + 3.0f)) * s * s + 1.0f;
    float s2 = 2.0f - t;
    w3 = ((AA * s2 - 5.0f * AA) * s2 + 8.0f * AA) * s2 - 4.0f * AA;
}

// rare fallback (~1e-4 of pixels): reflected global taps for TWO channels
__device__ __noinline__ float px_slow2(const float* __restrict__ tgt_p,
                                       const float* __restrict__ in_p, int pix,
                                       int bx, int by, float wx0, float wx1,
                                       float wx2, float wx3, float wy0,
                                       float wy1, float wy2, float wy3) {
    const int r0 = reflect_small(by - 1) * WW;
    const int r1 = reflect_small(by) * WW;
    const int r2 = reflect_small(by + 1) * WW;
    const int r3 = reflect_small(by + 2) * WW;
    const int c0 = reflect_small(bx - 1);
    const int c1 = reflect_small(bx);
    const int c2 = reflect_small(bx + 1);
    const int c3 = reflect_small(bx + 2);
    float acc = 0.0f;
#pragma unroll
    for (int c = 0; c < 2; ++c) {
        const float* tb = tgt_p + c * HW;
        float q0 = wx0 * tb[r0 + c0] + wx1 * tb[r0 + c1] + wx2 * tb[r0 + c2] +
                   wx3 * tb[r0 + c3];
        float q1 = wx0 * tb[r1 + c0] + wx1 * tb[r1 + c1] + wx2 * tb[r1 + c2] +
                   wx3 * tb[r1 + c3];
        float q2 = wx0 * tb[r2 + c0] + wx1 * tb[r2 + c1] + wx2 * tb[r2 + c2] +
                   wx3 * tb[r2 + c3];
        float q3 = wx0 * tb[r3 + c0] + wx1 * tb[r3 + c1] + wx2 * tb[r3 + c2] +
                   wx3 * tb[r3 + c3];
        float v = wy0 * q0 + wy1 * q1 + wy2 * q2 + wy3 * q3;
        acc += fabsf(in_p[c * HW + pix] - v);
    }
    return acc;
}

__global__ __launch_bounds__(256, 4) void warp_loss_k(
    const float* __restrict__ input, const float* __restrict__ target,
    const float* __restrict__ flow, float* __restrict__ wsbuf) {
    __shared__ float cache[2 * CH_STRIDE];    // 34.8 KB
    const int tid = (int)threadIdx.x;
    const int wv = tid >> 6, lane = tid & 63;

    // pair bit HIGH so pair partners (idx +/-512) land on the same XCD (mod 8)
    const int low = (int)blockIdx.x & 511;
    const int pair = (int)blockIdx.x >> 9;    // 0: ch {0,1}, 1: ch {2,3}
    const int colid = low >> 4;               // (b, chunk)
    const int strip = low & 15;
    const int b = colid >> 2;
    const int chunk = colid & 3;
    const int x0 = CROP + chunk * 256;
    // window start col: 4-aligned, [wscol, wscol+271] in-image, ~±7σ margins
    const int wscol = chunk == 0 ? 0 : chunk == 1 ? 252 : chunk == 2 ? 508 : 752;
    const int y0 = CROP + strip * 64;
    const int y1 = min(y0 + 64, CROP + HC);   // exclusive; strip length even

    const int x = x0 + tid;
    const bool valid_px = x <= 1018;
    const int xc = valid_px ? x : 1018;

    // base pointers for this block's channel pair
    const float* tgt_p = target + (size_t)b * CC * HW + (size_t)(pair * 2) * HW;
    const float* in_p = input + (size_t)b * CC * HW + (size_t)(pair * 2) * HW;
    const float* flow_b = flow + (size_t)b * 2 * HW;

    // wave wv stages channel (wv>>1), part (wv&1): part0 = floats [0,255]
    // via 16B/lane; part1 = floats [208,271] via 4B/lane (overlap identical)
    const int chv = wv >> 1, part = wv & 1;
    const float* plane = tgt_p + (size_t)chv * HW;
    const int chbase = chv * CH_STRIDE;

    // prologue: rows y0-5 .. y0+6 (12 rows; all in [0,1023] -> no reflection)
#pragma unroll 1
    for (int k = 0; k < 12; ++k) {
        const int r = y0 - 5 + k;
        const int slot = r & (RING - 1);
        const float* src = plane + (size_t)r * WW + wscol;
        if (part == 0) {
            __builtin_amdgcn_global_load_lds(
                (gv_t*)(src + lane * 4), (lv_t*)&cache[chbase + slot * SWID],
                16, 0, 0);
        } else {
            __builtin_amdgcn_global_load_lds(
                (gv_t*)(src + 208 + lane),
                (lv_t*)&cache[chbase + slot * SWID + 208], 4, 0, 0);
        }
    }

    // scalar-stream prefetch for first row pair
    float dx0n, dy0n, i00n, i01n, dx1n, dy1n, i10n, i11n;
    {
        const int p0 = y0 * WW + xc;
        const int p1 = (y0 + 1) * WW + xc;
        dx0n = flow_b[p0];
        dy0n = flow_b[HW + p0];
        i00n = in_p[p0];
        i01n = in_p[HW + p0];
        dx1n = flow_b[p1];
        dy1n = flow_b[HW + p1];
        i10n = in_p[p1];
        i11n = in_p[HW + p1];
    }

    __syncthreads();

    float lsum = 0.0f;

    for (int y = y0; y < y1; y += 2) {
        // consume prefetched scalar streams for rows y, y+1
        const float dx0 = dx0n, dy0 = dy0n, i00 = i00n, i01 = i01n;
        const float dx1 = dx1n, dy1 = dy1n, i10 = i10n, i11 = i11n;

        // issue next pair's scalar prefetch NOW (consumed after next barrier)
        {
            const int yn = (y + 2 < y1) ? y + 2 : y;
            const int p0 = yn * WW + xc;
            const int p1 = (yn + 1) * WW + xc;
            dx0n = flow_b[p0];
            dy0n = flow_b[HW + p0];
            i00n = in_p[p0];
            i01n = in_p[HW + p0];
            dx1n = flow_b[p1];
            dy1n = flow_b[HW + p1];
            i10n = in_p[p1];
            i11n = in_p[HW + p1];
        }

        // stage rows y+7, y+8 (their slots hold rows y-9, y-8 — both outside
        // the read window [y-5, y+6])
#pragma unroll
        for (int rr = 0; rr < 2; ++rr) {
            const int r = y + 7 + rr;
            if (r < HH) {   // wave-uniform; last strip tail
                const int slot = r & (RING - 1);
                const float* src = plane + (size_t)r * WW + wscol;
                if (part == 0) {
                    __builtin_amdgcn_global_load_lds(
                        (gv_t*)(src + lane * 4),
                        (lv_t*)&cache[chbase + slot * SWID], 16, 0, 0);
                } else {
                    __builtin_amdgcn_global_load_lds(
                        (gv_t*)(src + 208 + lane),
                        (lv_t*)&cache[chbase + slot * SWID + 208], 4, 0, 0);
                }
            }
        }

        // ---- pixel 0 (row y): taps must lie in [y-5, y+6] -> d in [-4, 4]
        {
            const int pix = y * WW + xc;
            const float fx = (float)xc + dx0;
            const float fy = (float)y + dy0;
            const float bxf = floorf(fx), byf = floorf(fy);
            const int bx = (int)bxf, by = (int)byf;
            const float tx = fx - bxf, ty = fy - byf;

            float wx0, wx1, wx2, wx3, wy0, wy1, wy2, wy3;
            cubic_w(tx, wx0, wx1, wx2, wx3);
            cubic_w(ty, wy0, wy1, wy2, wy3);

            const int d = by - y;
            const int cx = bx - 1 - wscol;
            const bool fast =
                valid_px & (d >= -4) & (d <= 4) & (cx >= 0) & (cx <= 268);

            if (fast) {
                const int t = (by - 1) & (RING - 1);
                float v0 = 0.0f, v1 = 0.0f;
#pragma unroll
                for (int j = 0; j < 4; ++j) {
                    const int s = (t + j) & (RING - 1);
                    const int base = s * SWID + cx;
                    const float wyj =
                        j == 0 ? wy0 : j == 1 ? wy1 : j == 2 ? wy2 : wy3;
                    const float* p0 = &cache[base];
                    const float* p1 = &cache[CH_STRIDE + base];
                    v0 += wyj * (p0[0] * wx0 + p0[1] * wx1 + p0[2] * wx2 +
                                 p0[3] * wx3);
                    v1 += wyj * (p1[0] * wx0 + p1[1] * wx1 + p1[2] * wx2 +
                                 p1[3] * wx3);
                }
                lsum += fabsf(i00 - v0) + fabsf(i01 - v1);
            } else if (valid_px) {
                lsum += px_slow2(tgt_p, in_p, pix, bx, by, wx0, wx1, wx2, wx3,
                                 wy0, wy1, wy2, wy3);
            }
        }

        // ---- pixel 1 (row y+1): taps in [y-5, y+6] -> d1 in [-5, 3]
        {
            const int yb = y + 1;
            const int pix = yb * WW + xc;
            const float fx = (float)xc + dx1;
            const float fy = (float)yb + dy1;
            const float bxf = floorf(fx), byf = floorf(fy);
            const int bx = (int)bxf, by = (int)byf;
            const float tx = fx - bxf, ty = fy - byf;

            float wx0, wx1, wx2, wx3, wy0, wy1, wy2, wy3;
            cubic_w(tx, wx0, wx1, wx2, wx3);
            cubic_w(ty, wy0, wy1, wy2, wy3);

            const int d = by - yb;
            const int cx = bx - 1 - wscol;
            const bool fast =
                valid_px & (d >= -5) & (d <= 3) & (cx >= 0) & (cx <= 268);

            if (fast) {
                const int t = (by - 1) & (RING - 1);
                float v0 = 0.0f, v1 = 0.0f;
#pragma unroll
                for (int j = 0; j < 4; ++j) {
                    const int s = (t + j) & (RING - 1);
                    const int base = s * SWID + cx;
                    const float wyj =
                        j == 0 ? wy0 : j == 1 ? wy1 : j == 2 ? wy2 : wy3;
                    const float* p0 = &cache[base];
                    const float* p1 = &cache[CH_STRIDE + base];
                    v0 += wyj * (p0[0] * wx0 + p0[1] * wx1 + p0[2] * wx2 +
                                 p0[3] * wx3);
                    v1 += wyj * (p1[0] * wx0 + p1[1] * wx1 + p1[2] * wx2 +
                                 p1[3] * wx3);
                }
                lsum += fabsf(i10 - v0) + fabsf(i11 - v1);
            } else if (valid_px) {
                lsum += px_slow2(tgt_p, in_p, pix, bx, by, wx0, wx1, wx2, wx3,
                                 wy0, wy1, wy2, wy3);
            }
        }

        // staged rows landed + all reads of this window done before slot reuse
        __syncthreads();
    }

    // wave-64 shuffle reduction + per-block partial (no global atomic)
#pragma unroll
    for (int off2 = 32; off2 > 0; off2 >>= 1) lsum += __shfl_down(lsum, off2);

    __shared__ float sm[4];
    if (lane == 0) sm[wv] = lsum;
    __syncthreads();
    if (tid == 0) wsbuf[blockIdx.x] = sm[0] + sm[1] + sm[2] + sm[3];
}

__global__ __launch_bounds__(1024) void reduce_k(const float* __restrict__ ws,
                                                 float* __restrict__ out) {
    float s = 0.0f;
    for (int i = threadIdx.x; i < GRID; i += 1024) s += ws[i];
#pragma unroll
    for (int off = 32; off > 0; off >>= 1) s += __shfl_down(s, off);
    __shared__ float sm[16];
    const int lane = threadIdx.x & 63;
    const int wv = threadIdx.x >> 6;
    if (lane == 0) sm[wv] = s;
    __syncthreads();
    if (threadIdx.x == 0) {
        float t = 0.0f;
#pragma unroll
        for (int i = 0; i < 16; ++i) t += sm[i];
        constexpr float inv_count = 1.0f / ((float)BB * CC * HC * WC);
        out[0] = t * inv_count;
    }
}

extern "C" void kernel_launch(void* const* d_in, const int* in_sizes, int n_in,
                              void* d_out, int out_size, void* d_ws,
                              size_t ws_size, hipStream_t stream) {
    const float* input = (const float*)d_in[0];
    const float* target = (const float*)d_in[1];
    const float* flow = (const float*)d_in[2];
    float* ws = (float*)d_ws;
    float* out = (float*)d_out;

    warp_loss_k<<<GRID, 256, 0, stream>>>(input, target, flow, ws);
    reduce_k<<<1, 1024, 0, stream>>>(ws, out);
}